// Round 2
// baseline (282.470 us; speedup 1.0000x reference)
//
#include <hip/hip_runtime.h>
#include <math.h>

#define HH 256
#define WW 256
#define KC 32

// Basis init: one (h,k) pair per thread, spread over 32 blocks so it costs ~1-2us.
//   bHK[h*KC + k] = 2*cos(pi*(2h+1)*k/(2*256))   (stage-1: [h][k], wave-uniform row reads)
//   bLW[l*WW + w] = same value                    (stage-2: [l][w], contiguous reads)
__global__ void dct_basis_init(float* __restrict__ bHK, float* __restrict__ bLW) {
    int idx = blockIdx.x * blockDim.x + threadIdx.x;   // 0..8191
    int h = idx >> 5;
    int k = idx & 31;
    double arg = M_PI * (2.0 * (double)h + 1.0) * (double)k / (2.0 * (double)HH);
    float v = (float)(2.0 * cos(arg));
    bHK[h * KC + k] = v;
    bLW[k * WW + h] = v;
}

__device__ __forceinline__ void fma_block(float4 acc[KC], const float4 b[8], float4 xv) {
    #pragma unroll
    for (int j = 0; j < 8; ++j) {
        const float bk0 = b[j].x, bk1 = b[j].y, bk2 = b[j].z, bk3 = b[j].w;
        acc[4*j+0].x = fmaf(bk0, xv.x, acc[4*j+0].x);
        acc[4*j+0].y = fmaf(bk0, xv.y, acc[4*j+0].y);
        acc[4*j+0].z = fmaf(bk0, xv.z, acc[4*j+0].z);
        acc[4*j+0].w = fmaf(bk0, xv.w, acc[4*j+0].w);
        acc[4*j+1].x = fmaf(bk1, xv.x, acc[4*j+1].x);
        acc[4*j+1].y = fmaf(bk1, xv.y, acc[4*j+1].y);
        acc[4*j+1].z = fmaf(bk1, xv.z, acc[4*j+1].z);
        acc[4*j+1].w = fmaf(bk1, xv.w, acc[4*j+1].w);
        acc[4*j+2].x = fmaf(bk2, xv.x, acc[4*j+2].x);
        acc[4*j+2].y = fmaf(bk2, xv.y, acc[4*j+2].y);
        acc[4*j+2].z = fmaf(bk2, xv.z, acc[4*j+2].z);
        acc[4*j+2].w = fmaf(bk2, xv.w, acc[4*j+2].w);
        acc[4*j+3].x = fmaf(bk3, xv.x, acc[4*j+3].x);
        acc[4*j+3].y = fmaf(bk3, xv.y, acc[4*j+3].y);
        acc[4*j+3].z = fmaf(bk3, xv.z, acc[4*j+3].z);
        acc[4*j+3].w = fmaf(bk3, xv.w, acc[4*j+3].w);
    }
}

// One block (256 thr = 4 waves) per image.
// Stage 1: wave wv handles rows h = 4*i + wv (i=0..63); lane owns columns 4*lane..4*lane+3
//          (float4 coalesced loads, full row per wave). Basis row is wave-uniform
//          (readfirstlane) -> scalar loads on the free scalar pipe.
//          acc[k] is a full float4 per k: 128 VGPRs of accumulators per thread.
// Reduce:  4 partial T's summed via LDS in 4 k-chunks of 8.
// Stage 2: out[k][l] = sum_w T[k][w]*Cw[l][w], thread owns (k = tid>>3, 4 l's).
__global__ __launch_bounds__(256, 2) void dct_trunc_kernel(
    const float* __restrict__ x,
    const float* __restrict__ bHK,
    const float* __restrict__ bLW,
    float* __restrict__ out) {
    __shared__ float T[KC][WW + 4];    // 33280 B; +4 pad -> stage-2 reads broadcast per bank-quad
    __shared__ float R[4][8][WW];      // 32768 B reduction scratch

    const int tid  = threadIdx.x;
    const int lane = tid & 63;
    const int wv   = tid >> 6;
    const int img  = blockIdx.x;
    const float* __restrict__ xi = x + (size_t)img * (HH * WW);

    float4 acc[KC];
    #pragma unroll
    for (int k = 0; k < KC; ++k) acc[k] = make_float4(0.f, 0.f, 0.f, 0.f);

    // ---- Stage 1 ----
    const float* xp = xi + (size_t)wv * WW + lane * 4;
    float4 xv = *reinterpret_cast<const float4*>(xp);
    xp += 4 * WW;

    float4 b[8];
    {
        const float4* bp = reinterpret_cast<const float4*>(
            bHK + (size_t)__builtin_amdgcn_readfirstlane(wv) * KC);
        #pragma unroll
        for (int j = 0; j < 8; ++j) b[j] = bp[j];
    }

    for (int i = 0; i < 63; ++i) {
        // prefetch next row + next basis row before computing current
        float4 xn = *reinterpret_cast<const float4*>(xp);
        xp += 4 * WW;
        float4 bn[8];
        {
            const float4* bp = reinterpret_cast<const float4*>(
                bHK + (size_t)__builtin_amdgcn_readfirstlane(4 * (i + 1) + wv) * KC);
            #pragma unroll
            for (int j = 0; j < 8; ++j) bn[j] = bp[j];
        }
        fma_block(acc, b, xv);
        xv = xn;
        #pragma unroll
        for (int j = 0; j < 8; ++j) b[j] = bn[j];
    }
    fma_block(acc, b, xv);

    // ---- Cross-wave reduction into T, 4 chunks of 8 k's ----
    #pragma unroll 1
    for (int c = 0; c < 4; ++c) {
        #pragma unroll
        for (int kk = 0; kk < 8; ++kk)
            *reinterpret_cast<float4*>(&R[wv][kk][lane * 4]) = acc[c * 8 + kk];
        __syncthreads();
        #pragma unroll
        for (int p = 0; p < 2; ++p) {
            int kk = wv + 4 * p;   // each wave reduces 2 of the 8 k's, same lane->w map
            float4 s0 = *reinterpret_cast<const float4*>(&R[0][kk][lane * 4]);
            float4 s1 = *reinterpret_cast<const float4*>(&R[1][kk][lane * 4]);
            float4 s2 = *reinterpret_cast<const float4*>(&R[2][kk][lane * 4]);
            float4 s3 = *reinterpret_cast<const float4*>(&R[3][kk][lane * 4]);
            float4 s;
            s.x = (s0.x + s1.x) + (s2.x + s3.x);
            s.y = (s0.y + s1.y) + (s2.y + s3.y);
            s.z = (s0.z + s1.z) + (s2.z + s3.z);
            s.w = (s0.w + s1.w) + (s2.w + s3.w);
            *reinterpret_cast<float4*>(&T[c * 8 + kk][lane * 4]) = s;
        }
        __syncthreads();
    }

    // ---- Stage 2 ----
    const int k  = tid >> 3;
    const int l4 = (tid & 7) * 4;
    float4 a2 = make_float4(0.f, 0.f, 0.f, 0.f);

    const float* __restrict__ c0p = bLW + (l4 + 0) * WW;
    const float* __restrict__ c1p = bLW + (l4 + 1) * WW;
    const float* __restrict__ c2p = bLW + (l4 + 2) * WW;
    const float* __restrict__ c3p = bLW + (l4 + 3) * WW;

    #pragma unroll 4
    for (int w = 0; w < WW; w += 4) {
        float4 tv = *reinterpret_cast<const float4*>(&T[k][w]);
        float4 c0 = *reinterpret_cast<const float4*>(&c0p[w]);
        float4 c1 = *reinterpret_cast<const float4*>(&c1p[w]);
        float4 c2 = *reinterpret_cast<const float4*>(&c2p[w]);
        float4 c3 = *reinterpret_cast<const float4*>(&c3p[w]);
        a2.x = fmaf(tv.x, c0.x, fmaf(tv.y, c0.y, fmaf(tv.z, c0.z, fmaf(tv.w, c0.w, a2.x))));
        a2.y = fmaf(tv.x, c1.x, fmaf(tv.y, c1.y, fmaf(tv.z, c1.z, fmaf(tv.w, c1.w, a2.y))));
        a2.z = fmaf(tv.x, c2.x, fmaf(tv.y, c2.y, fmaf(tv.z, c2.z, fmaf(tv.w, c2.w, a2.z))));
        a2.w = fmaf(tv.x, c3.x, fmaf(tv.y, c3.y, fmaf(tv.z, c3.z, fmaf(tv.w, c3.w, a2.w))));
    }

    *reinterpret_cast<float4*>(&out[(size_t)img * (KC * KC) + k * KC + l4]) = a2;
}

extern "C" void kernel_launch(void* const* d_in, const int* in_sizes, int n_in,
                              void* d_out, int out_size, void* d_ws, size_t ws_size,
                              hipStream_t stream) {
    const float* x = (const float*)d_in[0];
    float* out = (float*)d_out;

    float* bHK = (float*)d_ws;              // 256*32 floats
    float* bLW = bHK + HH * KC;             // 32*256 floats

    dct_basis_init<<<32, 256, 0, stream>>>(bHK, bLW);

    const int n_imgs = in_sizes[0] / (HH * WW);   // 1024
    dct_trunc_kernel<<<n_imgs, 256, 0, stream>>>(x, bHK, bLW, out);
}

// Round 3
// 178.117 us; speedup vs baseline: 1.5859x; 1.5859x over previous
//
#include <hip/hip_runtime.h>
#include <math.h>

#define HH 256
#define WW 256
#define KC 32
#define TP 260   // padded T row: stage-2 8 distinct k-rows land on disjoint bank-quads

// Basis init (fp64-accurate, unnormalized DCT-II matching torch_dct norm=None):
//   bHK[h*KC + k] = 2*cos(pi*(2h+1)*k/(2*256))   (stage-1 layout [h][k])
//   bLW[l*WW + w] = same                          (stage-2 layout [l][w])
__global__ void dct_basis_init(float* __restrict__ bHK, float* __restrict__ bLW) {
    int idx = blockIdx.x * blockDim.x + threadIdx.x;   // 0..8191
    int h = idx >> 5;
    int k = idx & 31;
    double arg = M_PI * (2.0 * (double)h + 1.0) * (double)k / (2.0 * (double)HH);
    float v = (float)(2.0 * cos(arg));
    bHK[h * KC + k] = v;
    bLW[k * WW + h] = v;
}

// 8 FMAs x 4 columns; all indices compile-time after unroll (no scratch).
__device__ __forceinline__ void fma8(float4 acc[8], float4 b0, float4 b1, float4 xv) {
    float bk[8] = {b0.x, b0.y, b0.z, b0.w, b1.x, b1.y, b1.z, b1.w};
    #pragma unroll
    for (int j = 0; j < 8; ++j) {
        acc[j].x = fmaf(bk[j], xv.x, acc[j].x);
        acc[j].y = fmaf(bk[j], xv.y, acc[j].y);
        acc[j].z = fmaf(bk[j], xv.z, acc[j].z);
        acc[j].w = fmaf(bk[j], xv.w, acc[j].w);
    }
}

// One block (4 waves) per image.
// Stage 1 (k-split): wave wv owns k in [8wv, 8wv+8); lane owns columns 4*lane..+3.
//   Streams all 256 rows (float4, coalesced; 4 waves in lockstep -> L1/L2 hot).
//   Basis rows read from LDS, wave-uniform address -> broadcast, zero conflicts.
//   acc[8] float4 = 32 VGPRs, statically indexed everywhere. No cross-wave reduce.
// LDS aliasing: bas[256][32] (32 KB) used in stage 1; T[32][260] (33.3 KB) used
//   after a barrier. max = 33.3 KB -> 4 blocks/CU.
__global__ __launch_bounds__(256, 4) void dct_trunc_kernel(
    const float* __restrict__ x,
    const float* __restrict__ bHK,
    const float* __restrict__ bLW,
    float* __restrict__ out) {
    __shared__ float sh[KC * TP];   // 8320 floats; bas = sh[h*32+k], T = sh[k*260+w]

    const int tid  = threadIdx.x;
    const int lane = tid & 63;
    const int wv   = tid >> 6;
    const int img  = blockIdx.x;
    const float* __restrict__ xi = x + (size_t)img * (HH * WW);

    // ---- Stage basis into LDS (2048 float4 / 256 threads = 8 each) ----
    {
        const float4* __restrict__ src = reinterpret_cast<const float4*>(bHK);
        float4* dst = reinterpret_cast<float4*>(sh);
        #pragma unroll
        for (int j = 0; j < 8; ++j) dst[tid + 256 * j] = src[tid + 256 * j];
    }
    __syncthreads();

    const int kb  = wv * 8;
    const int col = lane * 4;

    float4 acc[8];
    #pragma unroll
    for (int j = 0; j < 8; ++j) acc[j] = make_float4(0.f, 0.f, 0.f, 0.f);

    // ---- Stage 1: 64 chunks of 4 rows, 1-deep double buffer ----
    float4 cur0 = *reinterpret_cast<const float4*>(xi + 0 * WW + col);
    float4 cur1 = *reinterpret_cast<const float4*>(xi + 1 * WW + col);
    float4 cur2 = *reinterpret_cast<const float4*>(xi + 2 * WW + col);
    float4 cur3 = *reinterpret_cast<const float4*>(xi + 3 * WW + col);

    for (int i = 0; i < 63; ++i) {
        const float* xn = xi + (size_t)(4 * (i + 1)) * WW + col;
        float4 n0 = *reinterpret_cast<const float4*>(xn + 0 * WW);
        float4 n1 = *reinterpret_cast<const float4*>(xn + 1 * WW);
        float4 n2 = *reinterpret_cast<const float4*>(xn + 2 * WW);
        float4 n3 = *reinterpret_cast<const float4*>(xn + 3 * WW);

        const int h = 4 * i;
        fma8(acc, *reinterpret_cast<const float4*>(&sh[(h + 0) * KC + kb]),
                  *reinterpret_cast<const float4*>(&sh[(h + 0) * KC + kb + 4]), cur0);
        fma8(acc, *reinterpret_cast<const float4*>(&sh[(h + 1) * KC + kb]),
                  *reinterpret_cast<const float4*>(&sh[(h + 1) * KC + kb + 4]), cur1);
        fma8(acc, *reinterpret_cast<const float4*>(&sh[(h + 2) * KC + kb]),
                  *reinterpret_cast<const float4*>(&sh[(h + 2) * KC + kb + 4]), cur2);
        fma8(acc, *reinterpret_cast<const float4*>(&sh[(h + 3) * KC + kb]),
                  *reinterpret_cast<const float4*>(&sh[(h + 3) * KC + kb + 4]), cur3);

        cur0 = n0; cur1 = n1; cur2 = n2; cur3 = n3;
    }
    {   // last chunk: rows 252..255
        fma8(acc, *reinterpret_cast<const float4*>(&sh[252 * KC + kb]),
                  *reinterpret_cast<const float4*>(&sh[252 * KC + kb + 4]), cur0);
        fma8(acc, *reinterpret_cast<const float4*>(&sh[253 * KC + kb]),
                  *reinterpret_cast<const float4*>(&sh[253 * KC + kb + 4]), cur1);
        fma8(acc, *reinterpret_cast<const float4*>(&sh[254 * KC + kb]),
                  *reinterpret_cast<const float4*>(&sh[254 * KC + kb + 4]), cur2);
        fma8(acc, *reinterpret_cast<const float4*>(&sh[255 * KC + kb]),
                  *reinterpret_cast<const float4*>(&sh[255 * KC + kb + 4]), cur3);
    }

    __syncthreads();   // everyone done READING bas before T overwrites it

    #pragma unroll
    for (int j = 0; j < 8; ++j)
        *reinterpret_cast<float4*>(&sh[(kb + j) * TP + col]) = acc[j];
    __syncthreads();

    // ---- Stage 2: out[k][l] = sum_w T[k][w] * Cw[l][w] ----
    const int k  = tid >> 3;          // 0..31
    const int l4 = (tid & 7) * 4;     // 0,4,...,28
    float4 a2 = make_float4(0.f, 0.f, 0.f, 0.f);

    const float* __restrict__ c0p = bLW + (l4 + 0) * WW;
    const float* __restrict__ c1p = bLW + (l4 + 1) * WW;
    const float* __restrict__ c2p = bLW + (l4 + 2) * WW;
    const float* __restrict__ c3p = bLW + (l4 + 3) * WW;
    const float* __restrict__ tp  = &sh[k * TP];

    #pragma unroll 4
    for (int w = 0; w < WW; w += 4) {
        float4 tv = *reinterpret_cast<const float4*>(&tp[w]);
        float4 c0 = *reinterpret_cast<const float4*>(&c0p[w]);
        float4 c1 = *reinterpret_cast<const float4*>(&c1p[w]);
        float4 c2 = *reinterpret_cast<const float4*>(&c2p[w]);
        float4 c3 = *reinterpret_cast<const float4*>(&c3p[w]);
        a2.x = fmaf(tv.x, c0.x, fmaf(tv.y, c0.y, fmaf(tv.z, c0.z, fmaf(tv.w, c0.w, a2.x))));
        a2.y = fmaf(tv.x, c1.x, fmaf(tv.y, c1.y, fmaf(tv.z, c1.z, fmaf(tv.w, c1.w, a2.y))));
        a2.z = fmaf(tv.x, c2.x, fmaf(tv.y, c2.y, fmaf(tv.z, c2.z, fmaf(tv.w, c2.w, a2.z))));
        a2.w = fmaf(tv.x, c3.x, fmaf(tv.y, c3.y, fmaf(tv.z, c3.z, fmaf(tv.w, c3.w, a2.w))));
    }

    *reinterpret_cast<float4*>(&out[(size_t)img * (KC * KC) + k * KC + l4]) = a2;
}

extern "C" void kernel_launch(void* const* d_in, const int* in_sizes, int n_in,
                              void* d_out, int out_size, void* d_ws, size_t ws_size,
                              hipStream_t stream) {
    const float* x = (const float*)d_in[0];
    float* out = (float*)d_out;

    float* bHK = (float*)d_ws;              // 256*32 floats
    float* bLW = bHK + HH * KC;             // 32*256 floats

    dct_basis_init<<<32, 256, 0, stream>>>(bHK, bLW);

    const int n_imgs = in_sizes[0] / (HH * WW);   // 1024
    dct_trunc_kernel<<<n_imgs, 256, 0, stream>>>(x, bHK, bLW, out);
}

// Round 4
// 100.772 us; speedup vs baseline: 2.8031x; 1.7675x over previous
//
#include <hip/hip_runtime.h>
#include <math.h>

#define HH 256
#define WW 256
#define KC 32
#define TPAD 260        // padded T row: stage-2 reads for 8 k-groups hit disjoint banks
#define CHUNK 16        // rows per staged chunk
#define NCHUNK (HH / CHUNK)

// Async global->LDS, 16 B per lane. LDS dest is wave-uniform base + lane*16.
__device__ __forceinline__ void load_lds16(const float* g, float* l) {
    __builtin_amdgcn_global_load_lds(
        (const __attribute__((address_space(1))) unsigned int*)g,
        (__attribute__((address_space(3))) unsigned int*)l,
        16, 0, 0);
}

// One block (4 waves) per image.
// Stage 1 (k-split): wave wv owns k in [8wv,8wv+8); lane owns columns 4*lane..+3.
//   x rows staged once into LDS (double-buffered 16-row chunks, global_load_lds);
//   basis via Chebyshev recurrence in registers (8 chains/thread, cosf restart
//   every 64 rows) -> zero basis memory traffic.
// Stage 2: thread owns (k=tid>>3, l=l4..l4+3); T from LDS (float4), cw basis via
//   4 register recurrences over w. No global reads at all in stage 2.
// LDS: xbuf[2][16][256] (32 KB) aliased with T[32][260] (33.3 KB) -> 4 blocks/CU.
__global__ __launch_bounds__(256, 4) void dct_trunc_kernel(
    const float* __restrict__ x, float* __restrict__ out) {
    __shared__ float sh[KC * TPAD];   // 8320 floats = 33.3 KB

    const int tid  = threadIdx.x;
    const int lane = tid & 63;
    const int wv   = tid >> 6;
    const int img  = blockIdx.x;
    const float* __restrict__ xi = x + (size_t)img * (HH * WW);

    const int col = lane * 4;
    const int kb  = wv * 8;

    // Per-thread basis constants for the wave's 8 k's.
    float alpha[8], m[8], bc[8], bp[8];
    #pragma unroll
    for (int j = 0; j < 8; ++j) {
        float a  = (float)M_PI * (float)(kb + j) * (1.0f / 512.0f);
        alpha[j] = a;
        m[j]     = 2.0f * cosf(2.0f * a);
    }

    float4 acc[8];
    #pragma unroll
    for (int j = 0; j < 8; ++j) acc[j] = make_float4(0.f, 0.f, 0.f, 0.f);

    // Prologue: stage chunk 0 into buf 0 (wave wv loads rows 4wv..4wv+3).
    {
        const float* g = xi + (size_t)(4 * wv) * WW + col;
        float*       l = &sh[(4 * wv) * WW];
        #pragma unroll
        for (int r = 0; r < 4; ++r) load_lds16(g + r * WW, l + r * WW);
    }

    for (int c = 0; c < NCHUNK; ++c) {
        // Compiler-emitted vmcnt(0) drain here guarantees: chunk c resident,
        // and all waves are done reading buf[(c+1)&1] (last read at iter c-1).
        __syncthreads();

        if (c + 1 < NCHUNK) {   // issue next chunk; lands during this chunk's compute
            const float* g = xi + (size_t)((c + 1) * CHUNK + 4 * wv) * WW + col;
            float*       l = &sh[((c + 1) & 1) * (CHUNK * WW) + (4 * wv) * WW];
            #pragma unroll
            for (int r = 0; r < 4; ++r) load_lds16(g + r * WW, l + r * WW);
        }

        if ((c & 3) == 0) {     // restart recurrence every 64 rows (phase-drift control)
            const int h0 = c * CHUNK;
            #pragma unroll
            for (int j = 0; j < 8; ++j) {
                bc[j] = 2.0f * cosf((float)(2 * h0 + 1) * alpha[j]);
                bp[j] = 2.0f * cosf((float)(2 * h0 - 1) * alpha[j]);
            }
        }

        const float* xb = &sh[(c & 1) * (CHUNK * WW)];
        #pragma unroll 4
        for (int r = 0; r < CHUNK; ++r) {
            float4 xv = *reinterpret_cast<const float4*>(&xb[r * WW + col]);
            #pragma unroll
            for (int j = 0; j < 8; ++j) {
                acc[j].x = fmaf(bc[j], xv.x, acc[j].x);
                acc[j].y = fmaf(bc[j], xv.y, acc[j].y);
                acc[j].z = fmaf(bc[j], xv.z, acc[j].z);
                acc[j].w = fmaf(bc[j], xv.w, acc[j].w);
            }
            #pragma unroll
            for (int j = 0; j < 8; ++j) {   // advance: b[h+1] = m*b[h] - b[h-1]
                float bn = fmaf(m[j], bc[j], -bp[j]);
                bp[j] = bc[j];
                bc[j] = bn;
            }
        }
    }

    __syncthreads();   // stage-1 LDS reads complete -> safe to overwrite with T
    #pragma unroll
    for (int j = 0; j < 8; ++j)
        *reinterpret_cast<float4*>(&sh[(kb + j) * TPAD + col]) = acc[j];
    __syncthreads();

    // ---- Stage 2: out[k][l] = sum_w T[k][w] * 2cos(pi*(2w+1)l/512) ----
    const int k  = tid >> 3;
    const int l4 = (tid & 7) * 4;

    float la[4], lm[4], lc[4], lp[4];
    #pragma unroll
    for (int j = 0; j < 4; ++j) {
        float a = (float)M_PI * (float)(l4 + j) * (1.0f / 512.0f);
        la[j] = a;
        lm[j] = 2.0f * cosf(2.0f * a);
    }

    float4 a2 = make_float4(0.f, 0.f, 0.f, 0.f);
    const float* __restrict__ tp = &sh[k * TPAD];

    for (int wb = 0; wb < 4; ++wb) {          // restart every 64 w's
        const int w0 = wb * 64;
        #pragma unroll
        for (int j = 0; j < 4; ++j) {
            lc[j] = 2.0f * cosf((float)(2 * w0 + 1) * la[j]);
            lp[j] = 2.0f * cosf((float)(2 * w0 - 1) * la[j]);
        }
        #pragma unroll 4
        for (int w4 = 0; w4 < 16; ++w4) {
            float4 tv = *reinterpret_cast<const float4*>(&tp[w0 + w4 * 4]);
            #pragma unroll
            for (int s = 0; s < 4; ++s) {
                float t = (s == 0) ? tv.x : (s == 1) ? tv.y : (s == 2) ? tv.z : tv.w;
                a2.x = fmaf(t, lc[0], a2.x);
                a2.y = fmaf(t, lc[1], a2.y);
                a2.z = fmaf(t, lc[2], a2.z);
                a2.w = fmaf(t, lc[3], a2.w);
                #pragma unroll
                for (int j = 0; j < 4; ++j) {
                    float n = fmaf(lm[j], lc[j], -lp[j]);
                    lp[j] = lc[j];
                    lc[j] = n;
                }
            }
        }
    }

    *reinterpret_cast<float4*>(&out[(size_t)img * (KC * KC) + k * KC + l4]) = a2;
}

extern "C" void kernel_launch(void* const* d_in, const int* in_sizes, int n_in,
                              void* d_out, int out_size, void* d_ws, size_t ws_size,
                              hipStream_t stream) {
    const float* x = (const float*)d_in[0];
    float* out = (float*)d_out;
    const int n_imgs = in_sizes[0] / (HH * WW);   // 1024
    dct_trunc_kernel<<<n_imgs, 256, 0, stream>>>(x, out);
}

// Round 5
// 87.316 us; speedup vs baseline: 3.2350x; 1.1541x over previous
//
#include <hip/hip_runtime.h>
#include <math.h>

#define HH 256
#define WW 256
#define KC 32
#define TP 260   // padded T row: stage-2's 8 kk-groups read disjoint bank-quads

// Fully fused truncated 2D DCT, barrier-free main loop.
// Wave = (image, k-octet): 2048 blocks x 128 threads = 4096 independent waves.
//   bid&7 ~ XCD id (dispatch round-robin): img = xcd*128 + (idx>>1) puts all 4
//   octet-siblings of an image on ONE XCD, consecutively -> 3 of 4 image reads
//   hit that XCD's L2; HBM traffic stays ~268 MB.
// Stage 1 (rows): symmetry basis(255-h,k) = (-1)^k basis(h,k). Stream row pairs
//   (h, 255-h) top/bottom pointers, registers only; per pair: 8 add/sub + 32 FMA
//   (even k on sum, odd k on diff) + 8 Chebyshev-advance FMAs. cosf restart
//   every 64 pairs controls drift.
// Stage 2 (cols): same symmetry over w via per-wave T[8][260] in LDS.
__global__ __launch_bounds__(128, 4) void dct_trunc_kernel(
    const float* __restrict__ x, float* __restrict__ out, int ipx) {
    __shared__ float T[2][8][TP];   // per-wave private halves; 16.6 KB

    const int tid  = threadIdx.x;
    const int lane = tid & 63;
    const int wv   = tid >> 6;
    const int bid  = blockIdx.x;
    const int idx  = bid >> 3;
    const int img  = (bid & 7) * ipx + (idx >> 1);
    const int oct  = (idx & 1) * 2 + wv;     // 0..3
    const int kb   = oct * 8;
    const int col  = lane * 4;

    const float* __restrict__ xi = x + (size_t)img * (HH * WW);

    // Chebyshev constants for the octet's 8 k's: b(h) = 2cos((2h+1)*al),
    // b(h+1) = m2*b(h) - b(h-1), m2 = 2cos(2*al).
    float al[8], m2[8];
    #pragma unroll
    for (int j = 0; j < 8; ++j) {
        float a = (float)M_PI * (float)(kb + j) * (1.0f / 512.0f);
        al[j] = a;
        m2[j] = 2.0f * cosf(2.0f * a);
    }

    float4 acc[8];
    #pragma unroll
    for (int j = 0; j < 8; ++j) acc[j] = make_float4(0.f, 0.f, 0.f, 0.f);

    const float* pt = xi + col;              // row h (ascending)
    const float* pb = xi + 255 * WW + col;   // row 255-h (descending)

    float4 cT = *reinterpret_cast<const float4*>(pt);
    float4 cB = *reinterpret_cast<const float4*>(pb);

    float bc[8], bp[8];

    for (int g = 0; g < 2; ++g) {
        {   // restart recurrence at h = 64*g
            const float h2 = (float)(128 * g);
            #pragma unroll
            for (int j = 0; j < 8; ++j) {
                bc[j] = 2.0f * cosf((h2 + 1.0f) * al[j]);
                bp[j] = 2.0f * cosf((h2 - 1.0f) * al[j]);
            }
        }
        #pragma unroll 4
        for (int p = 0; p < 64; ++p) {
            // lookahead loads (last iter reads rows 128/127: in-bounds, unused)
            float4 nT = *reinterpret_cast<const float4*>(pt + WW);
            float4 nB = *reinterpret_cast<const float4*>(pb - WW);
            pt += WW; pb -= WW;

            float sx = cT.x + cB.x, sy = cT.y + cB.y;
            float sz = cT.z + cB.z, sw = cT.w + cB.w;
            float dx = cT.x - cB.x, dy = cT.y - cB.y;
            float dz = cT.z - cB.z, dw = cT.w - cB.w;

            #pragma unroll
            for (int j = 0; j < 8; j += 2) {     // even k -> sum
                acc[j].x = fmaf(bc[j], sx, acc[j].x);
                acc[j].y = fmaf(bc[j], sy, acc[j].y);
                acc[j].z = fmaf(bc[j], sz, acc[j].z);
                acc[j].w = fmaf(bc[j], sw, acc[j].w);
            }
            #pragma unroll
            for (int j = 1; j < 8; j += 2) {     // odd k -> diff
                acc[j].x = fmaf(bc[j], dx, acc[j].x);
                acc[j].y = fmaf(bc[j], dy, acc[j].y);
                acc[j].z = fmaf(bc[j], dz, acc[j].z);
                acc[j].w = fmaf(bc[j], dw, acc[j].w);
            }
            #pragma unroll
            for (int j = 0; j < 8; ++j) {        // advance chains
                float bn = fmaf(m2[j], bc[j], -bp[j]);
                bp[j] = bc[j]; bc[j] = bn;
            }
            cT = nT; cB = nB;
        }
    }

    // T transpose via LDS (wave-private region; one cheap barrier)
    #pragma unroll
    for (int j = 0; j < 8; ++j)
        *reinterpret_cast<float4*>(&T[wv][j][col]) = acc[j];
    __syncthreads();

    // ---- Stage 2: out[k][l] = sum_w T[k][w] * 2cos((2w+1)*pi*l/512) ----
    const int kk = lane >> 3;            // 0..7 within the octet
    const int l4 = (lane & 7) * 4;       // 0,4,...,28 (l4 even)
    const float* __restrict__ tp = &T[wv][kk][0];

    float bl[4], lm[4], lc[4], lp[4];
    #pragma unroll
    for (int j = 0; j < 4; ++j) {
        float b = (float)M_PI * (float)(l4 + j) * (1.0f / 512.0f);
        bl[j] = b;
        lm[j] = 2.0f * cosf(2.0f * b);
    }

    float4 a2 = make_float4(0.f, 0.f, 0.f, 0.f);

    for (int g = 0; g < 2; ++g) {
        {   // restart at w = 64*g
            const float w2 = (float)(128 * g);
            #pragma unroll
            for (int j = 0; j < 4; ++j) {
                lc[j] = 2.0f * cosf((w2 + 1.0f) * bl[j]);
                lp[j] = 2.0f * cosf((w2 - 1.0f) * bl[j]);
            }
        }
        #pragma unroll 4
        for (int q = 0; q < 16; ++q) {   // front w-quad: w = 64g+4q .. +3
            const int wf = 64 * g + 4 * q;
            float4 tf = *reinterpret_cast<const float4*>(&tp[wf]);
            float4 tb = *reinterpret_cast<const float4*>(&tp[252 - wf]);
            // pair (wf+e, 255-(wf+e)); back element for e is tb[3-e]
            float s0 = tf.x + tb.w, d0 = tf.x - tb.w;
            float s1 = tf.y + tb.z, d1 = tf.y - tb.z;
            float s2 = tf.z + tb.y, d2 = tf.z - tb.y;
            float s3 = tf.w + tb.x, d3 = tf.w - tb.x;
            #pragma unroll
            for (int e = 0; e < 4; ++e) {
                float se = (e == 0) ? s0 : (e == 1) ? s1 : (e == 2) ? s2 : s3;
                float de = (e == 0) ? d0 : (e == 1) ? d1 : (e == 2) ? d2 : d3;
                a2.x = fmaf(lc[0], se, a2.x);   // l4   even -> sum
                a2.y = fmaf(lc[1], de, a2.y);   // l4+1 odd  -> diff
                a2.z = fmaf(lc[2], se, a2.z);   // l4+2 even -> sum
                a2.w = fmaf(lc[3], de, a2.w);   // l4+3 odd  -> diff
                #pragma unroll
                for (int j = 0; j < 4; ++j) {
                    float n = fmaf(lm[j], lc[j], -lp[j]);
                    lp[j] = lc[j]; lc[j] = n;
                }
            }
        }
    }

    *reinterpret_cast<float4*>(
        &out[(size_t)img * (KC * KC) + (kb + kk) * KC + l4]) = a2;
}

extern "C" void kernel_launch(void* const* d_in, const int* in_sizes, int n_in,
                              void* d_out, int out_size, void* d_ws, size_t ws_size,
                              hipStream_t stream) {
    const float* x = (const float*)d_in[0];
    float* out = (float*)d_out;
    const int n_imgs = in_sizes[0] / (HH * WW);   // 1024
    const int ipx = n_imgs >> 3;                  // images per XCD slice
    dct_trunc_kernel<<<n_imgs * 2, 128, 0, stream>>>(x, out, ipx);
}

// Round 8
// 50.266 us; speedup vs baseline: 5.6195x; 1.7371x over previous
//
#include <hip/hip_runtime.h>
#include <math.h>

#define KC 32

typedef __attribute__((ext_vector_type(8))) short bf16x8;
typedef __attribute__((ext_vector_type(4))) float f32x4;

__device__ __forceinline__ unsigned pack2_bf16(float a, float b) {
    unsigned ua = __float_as_uint(a); ua += 0x7fffu + ((ua >> 16) & 1u);
    unsigned ub = __float_as_uint(b); ub += 0x7fffu + ((ub >> 16) & 1u);
    return (ua >> 16) | (ub & 0xffff0000u);
}

// One 16-KB table of pre-packed MFMA basis fragments (uint4 per lane):
//   frag[(c*2+sub)*64 + lane], elem i = bf16(2*cos(pi*(2*A+1)*B/512)),
//   A = 32c + 8*(lane>>4) + i, B = sub*16 + (lane&15).
// Serves stage 1 (A=w, B=l: Cw B-operand) AND stage 2 (A=h, B=k: Ch A-operand).
__global__ void basis_init(unsigned short* tab) {
    const int t = blockIdx.x * 256 + threadIdx.x;   // 0..1023
    const int c = t >> 7, sub = (t >> 6) & 1, lane = t & 63;
    const int g = lane >> 4, cl = lane & 15;
    #pragma unroll
    for (int i = 0; i < 8; ++i) {
        int A = 32 * c + 8 * g + i;
        int B = sub * 16 + cl;
        double v = 2.0 * cos(M_PI * (double)(2 * A + 1) * (double)B / 512.0);
        float f = (float)v;
        unsigned u = __float_as_uint(f);
        u += 0x7fffu + ((u >> 16) & 1u);
        tab[t * 8 + i] = (unsigned short)(u >> 16);
    }
}

// Block = 256 thr = 4 waves = 1 image.
// Stage 1: U[256 h][32 l] = X @ Cw^T. K = w (8 chunks of 32). X-chunk staged
//   fp32->bf16 into a 2x20KB LDS ring, row-major [256 h][32 w] padded to 80 B/row
//   (pad => both ds_write_b64 staging and ds_read_b128 A-frags hit the dense
//   8-access/bank floor; no swizzle). A-frag = 8 contiguous w per lane (the
//   refcheck'd contiguous-8 k-map); B-frag = table. Wave wv owns m-tiles
//   {wv,wv+4,wv+8,wv+12}, both n-tiles; acc = 8 x f32x4.
// U^T [32 l][256 h] bf16, 528 B/row, aliased onto ring buf0.
// Stage 2: out[32 k][32 l] = Ch @ U. A-frag = table, B-frag = ds_read_b128 from
//   U^T (contiguous h). Wave = (mt2 = wv>>1, nt2 = wv&1), 8 MFMAs, direct global out.
__global__ __launch_bounds__(256, 4) void dct_trunc_kernel(
    const float* __restrict__ x, float* __restrict__ out,
    const unsigned short* __restrict__ tab) {
    __shared__ uint4 ldsbuf[2560];                  // 40 KB
    char* lds = (char*)ldsbuf;
    const bf16x8* __restrict__ tabv = (const bf16x8*)tab;

    const int tid  = threadIdx.x;
    const int lane = tid & 63;
    const int wv   = tid >> 6;
    const int g    = lane >> 4;
    const int cl   = lane & 15;
    const int img  = blockIdx.x;
    const float* __restrict__ xi = x + (size_t)img * 65536;

    // staging assignment: thread covers rows {srow, srow+32, ..., srow+224},
    // w-segment sc*4..sc*4+3 of the 32-w chunk (8 lanes x float4 = 128 B/row).
    const int srow = tid >> 3;      // 0..31
    const int sc   = tid & 7;       // 0..7

    float4 pf0, pf1, pf2, pf3, pf4, pf5, pf6, pf7;

#define STAGE_LOAD(c_) do { \
    const float* s_ = xi + (size_t)(c_) * 32 + (size_t)srow * 256 + sc * 4; \
    pf0 = *(const float4*)(s_ + 0 * 8192); \
    pf1 = *(const float4*)(s_ + 1 * 8192); \
    pf2 = *(const float4*)(s_ + 2 * 8192); \
    pf3 = *(const float4*)(s_ + 3 * 8192); \
    pf4 = *(const float4*)(s_ + 4 * 8192); \
    pf5 = *(const float4*)(s_ + 5 * 8192); \
    pf6 = *(const float4*)(s_ + 6 * 8192); \
    pf7 = *(const float4*)(s_ + 7 * 8192); \
} while (0)

#define STAGE_WRITE(base_) do { \
    char* b_ = lds + (base_) + srow * 80 + sc * 8; \
    *(uint2*)(b_ + 0 * 2560) = make_uint2(pack2_bf16(pf0.x, pf0.y), pack2_bf16(pf0.z, pf0.w)); \
    *(uint2*)(b_ + 1 * 2560) = make_uint2(pack2_bf16(pf1.x, pf1.y), pack2_bf16(pf1.z, pf1.w)); \
    *(uint2*)(b_ + 2 * 2560) = make_uint2(pack2_bf16(pf2.x, pf2.y), pack2_bf16(pf2.z, pf2.w)); \
    *(uint2*)(b_ + 3 * 2560) = make_uint2(pack2_bf16(pf3.x, pf3.y), pack2_bf16(pf3.z, pf3.w)); \
    *(uint2*)(b_ + 4 * 2560) = make_uint2(pack2_bf16(pf4.x, pf4.y), pack2_bf16(pf4.z, pf4.w)); \
    *(uint2*)(b_ + 5 * 2560) = make_uint2(pack2_bf16(pf5.x, pf5.y), pack2_bf16(pf5.z, pf5.w)); \
    *(uint2*)(b_ + 6 * 2560) = make_uint2(pack2_bf16(pf6.x, pf6.y), pack2_bf16(pf6.z, pf6.w)); \
    *(uint2*)(b_ + 7 * 2560) = make_uint2(pack2_bf16(pf7.x, pf7.y), pack2_bf16(pf7.z, pf7.w)); \
} while (0)

    f32x4 a00 = {0.f,0.f,0.f,0.f}, a01 = a00, a10 = a00, a11 = a00;
    f32x4 a20 = a00, a21 = a00, a30 = a00, a31 = a00;

    // Prologue: chunk 0 -> buf 0
    STAGE_LOAD(0);
    STAGE_WRITE(0);

    const int frow = cl * 80 + g * 16;   // A-frag byte offset within a 16-row tile... (row = mt*16+cl)

    #pragma unroll 2
    for (int c = 0; c < 8; ++c) {
        __syncthreads();                 // chunk c resident; buf (c+1)&1 free

        bf16x8 bf0 = tabv[(c * 2 + 0) * 64 + lane];   // Cw frags (L1/L2-hot)
        bf16x8 bf1 = tabv[(c * 2 + 1) * 64 + lane];
        if (c < 7) STAGE_LOAD(c + 1);    // issue early; lands under MFMAs

        const char* xb = lds + (c & 1) * 20480;
        bf16x8 xf0 = *(const bf16x8*)(xb + (wv +  0) * 1280 + frow);
        bf16x8 xf1 = *(const bf16x8*)(xb + (wv +  4) * 1280 + frow);
        bf16x8 xf2 = *(const bf16x8*)(xb + (wv +  8) * 1280 + frow);
        bf16x8 xf3 = *(const bf16x8*)(xb + (wv + 12) * 1280 + frow);

        a00 = __builtin_amdgcn_mfma_f32_16x16x32_bf16(xf0, bf0, a00, 0, 0, 0);
        a01 = __builtin_amdgcn_mfma_f32_16x16x32_bf16(xf0, bf1, a01, 0, 0, 0);
        a10 = __builtin_amdgcn_mfma_f32_16x16x32_bf16(xf1, bf0, a10, 0, 0, 0);
        a11 = __builtin_amdgcn_mfma_f32_16x16x32_bf16(xf1, bf1, a11, 0, 0, 0);
        a20 = __builtin_amdgcn_mfma_f32_16x16x32_bf16(xf2, bf0, a20, 0, 0, 0);
        a21 = __builtin_amdgcn_mfma_f32_16x16x32_bf16(xf2, bf1, a21, 0, 0, 0);
        a30 = __builtin_amdgcn_mfma_f32_16x16x32_bf16(xf3, bf0, a30, 0, 0, 0);
        a31 = __builtin_amdgcn_mfma_f32_16x16x32_bf16(xf3, bf1, a31, 0, 0, 0);

        if (c < 7) STAGE_WRITE(((c + 1) & 1) * 20480);
    }

    // ---- U^T write: [32 l][256 h] bf16, 528 B rows, aliased on buf0.
    // buf0's last reads were chunk 6, fenced by the barrier at top of c=7.
    // C/D layout: col = cl (= l within n-tile), row = 4g + r (= h within m-tile).
#define UTW(q_, A0_, A1_) do { \
    char* u0 = lds + (0 * 16 + cl) * 528 + (wv + 4 * (q_)) * 32 + g * 8; \
    char* u1 = lds + (1 * 16 + cl) * 528 + (wv + 4 * (q_)) * 32 + g * 8; \
    *(uint2*)u0 = make_uint2(pack2_bf16(A0_[0], A0_[1]), pack2_bf16(A0_[2], A0_[3])); \
    *(uint2*)u1 = make_uint2(pack2_bf16(A1_[0], A1_[1]), pack2_bf16(A1_[2], A1_[3])); \
} while (0)
    UTW(0, a00, a01);
    UTW(1, a10, a11);
    UTW(2, a20, a21);
    UTW(3, a30, a31);
    __syncthreads();

    // ---- Stage 2: out = Ch @ U (K = h, 8 chunks) ----
    const int mt2 = wv >> 1;
    const int nt2 = wv & 1;
    f32x4 acc2 = {0.f, 0.f, 0.f, 0.f};
    const char* ub = lds + (nt2 * 16 + cl) * 528 + g * 16;
    #pragma unroll
    for (int c2 = 0; c2 < 8; ++c2) {
        bf16x8 af = tabv[(c2 * 2 + mt2) * 64 + lane];           // Ch frag
        bf16x8 uf = *(const bf16x8*)(ub + c2 * 64);             // U^T, contiguous h
        acc2 = __builtin_amdgcn_mfma_f32_16x16x32_bf16(af, uf, acc2, 0, 0, 0);
    }

    float* op = out + (size_t)img * 1024 + (mt2 * 16 + g * 4) * 32 + nt2 * 16 + cl;
    op[0]  = acc2[0];
    op[32] = acc2[1];
    op[64] = acc2[2];
    op[96] = acc2[3];
}

extern "C" void kernel_launch(void* const* d_in, const int* in_sizes, int n_in,
                              void* d_out, int out_size, void* d_ws, size_t ws_size,
                              hipStream_t stream) {
    const float* x = (const float*)d_in[0];
    float* out = (float*)d_out;
    unsigned short* tab = (unsigned short*)d_ws;    // 16 KB fragment table

    basis_init<<<4, 256, 0, stream>>>(tab);
    const int n_imgs = in_sizes[0] / 65536;         // 1024
    dct_trunc_kernel<<<n_imgs, 256, 0, stream>>>(x, out, tab);
}